// Round 3
// baseline (67.151 us; speedup 1.0000x reference)
//
#include <hip/hip_runtime.h>

// RegionProposal, fully fused single-block kernel.
// decode 55296 anchors -> stable top-6000 by score -> greedy NMS (IoU>0.7) ->
// first 300 kept boxes zero-padded to [300,4] fp32.
//
// Phases (1 block x 1024 threads, all state in LDS):
//  A: fs = flip32(class-1 logit) read straight from cls (coalesced), 16384-bin
//     LDS histogram of fs>>18.
//  B: shuffle-based scan of per-thread 16-bin sums -> rank-512 (B1) and
//     rank-6000 (B2) cutoff bins.
//  C: recompute fs, compact keys (fs<<32 | anchor_idx) into LDS: S region
//     (bin<=B1, ~520) front, L region back. Wave-aggregated atomics.
//  D: bitonic sort of S (1024 slots); j<=32 stages in-register via shfl_xor
//     (15 barrier phases instead of 55). Decode S boxes into LDS sbox/sarea.
//  E: chunked 16-wave NMS (64 cand/chunk): vs-kept strided over waves,
//     in-chunk 64x64 pairwise split over waves, greedy order resolved by
//     iterated-ballot fixed point on wave 0. Early exit at 300 kept.
//  Fallback (giant tie bins / low keep-rate): full 8192 bitonic + NMS with
//  per-chunk on-the-fly decode. Rare; correctness only.
//
// Key = (flip32(logit)<<32) | idx: ascending u64 == descending logit, ties by
// ascending index == stable argsort(-sigmoid(logit)) (sigmoid monotone).
// Decode math identical to round-1/2 kernels (absmax 0.0).

#define ADIM 9
#define NANCH 55296
#define HWSZ 6144
#define TOPK 6000
#define OUTK 300
#define NBINS 16384
#define CAP 8192
#define SCAP 1024
#define LCAP 7168      // CAP - SCAP
#define RANK1 512
#define THR 0.7f

typedef unsigned long long u64;
typedef unsigned int u32;

__device__ __forceinline__ u32 flip32(float f) {
    u32 b = __float_as_uint(f);
    u32 u = (b & 0x80000000u) ? ~b : (b | 0x80000000u);
    return ~u;                     // ascending fs == descending f
}

__device__ __forceinline__ bool iou_gt(float4 a, float aa, float4 b, float ba) {
    float ix = fminf(a.z, b.z) - fmaxf(a.x, b.x);
    float iy = fminf(a.w, b.w) - fmaxf(a.y, b.y);
    float inter = fmaxf(ix, 0.f) * fmaxf(iy, 0.f);
    float uni = aa + ba - inter;
    return inter / fmaxf(uni, 1e-12f) > THR;
}

__device__ __forceinline__ float4 decode_box(const float* __restrict__ loc,
                                             const float* __restrict__ anc, u32 n) {
    u32 a = n % ADIM, hw = n / ADIM;
    float t0 = loc[(4 * a + 0) * HWSZ + hw];
    float t1 = loc[(4 * a + 1) * HWSZ + hw];
    float t2 = loc[(4 * a + 2) * HWSZ + hw];
    float t3 = loc[(4 * a + 3) * HWSZ + hw];
    float4 an = reinterpret_cast<const float4*>(anc)[n];
    float cx = t0 * an.z + an.x;
    float cy = t1 * an.w + an.y;
    float bw = expf(t2) * an.z;
    float bh = expf(t3) * an.w;
    return make_float4(fminf(fmaxf(cx - bw * 0.5f, 0.f), 1.f),
                       fminf(fmaxf(cy - bh * 0.5f, 0.f), 1.f),
                       fminf(fmaxf(cx + bw * 0.5f, 0.f), 1.f),
                       fminf(fmaxf(cy + bh * 0.5f, 0.f), 1.f));
}

__device__ __forceinline__ u64 sx64(u64 v, int m) {
    u32 lo = __shfl_xor((u32)(v & 0xffffffffu), m, 64);
    u32 hi = __shfl_xor((u32)(v >> 32), m, 64);
    return ((u64)hi << 32) | lo;
}

// one bitonic compare-exchange step in-register; lane holds position seg*64+lane
__device__ __forceinline__ u64 ce64(u64 v, int j, int lane, bool up) {
    u64 pv = sx64(v, j);
    u64 mn = (pv < v) ? pv : v;
    u64 mx = (pv < v) ? v : pv;
    return (((lane & j) == 0) == up) ? mn : mx;
}

__global__ void __launch_bounds__(1024) k_mega(const float* __restrict__ cls,
                                               const float* __restrict__ loc,
                                               const float* __restrict__ anc,
                                               float4* __restrict__ out) {
    __shared__ u64 cand[CAP];         // 64 KB; aliased as u32 hist[16384] in A/B
    __shared__ float4 sbox[SCAP];     // 16 KB
    __shared__ float  sarea[SCAP];    // 4 KB
    __shared__ float4 kept[OUTK];
    __shared__ float  karea[OUTK];
    __shared__ float4 cbox[64];       // fallback chunk boxes
    __shared__ float  carea[64];
    __shared__ u64 supw[16];
    __shared__ u64 sbyp[1024];        // 8 KB
    __shared__ u32 wsum[16];
    __shared__ u32 shu[8];            // 0:cntS 1:cntL 2:B1 3:B2 4:kc 5:i0

    const int tid = threadIdx.x;
    const int wid = tid >> 6;
    const int lane = tid & 63;
    u32* hist = (u32*)cand;

    // ---- A: histogram ----
    for (int i = tid; i < NBINS; i += 1024) hist[i] = 0;
    if (tid < 8) shu[tid] = 0;
    __syncthreads();
    for (int a = 0; a < ADIM; ++a) {
        const float* base = cls + (2 * a + 1) * HWSZ;
        for (int r = 0; r < 6; ++r)
            atomicAdd(&hist[flip32(base[r * 1024 + tid]) >> 18], 1u);
    }
    __syncthreads();

    // ---- B: scan + cutoff bins ----
    {
        int b0 = tid * 16;
        u32 s = 0;
        #pragma unroll
        for (int b = 0; b < 16; ++b) s += hist[b0 + b];
        u32 x = s;
        #pragma unroll
        for (int d = 1; d < 64; d <<= 1) {
            u32 y = __shfl_up(x, (unsigned)d, 64);
            if (lane >= d) x += y;
        }
        if (lane == 63) wsum[wid] = x;
        __syncthreads();
        if (wid == 0) {
            u32 w = (lane < 16) ? wsum[lane] : 0u;
            #pragma unroll
            for (int d = 1; d < 16; d <<= 1) {
                u32 y = __shfl_up(w, (unsigned)d, 64);
                if (lane >= d) w += y;
            }
            if (lane < 16) wsum[lane] = w;
        }
        __syncthreads();
        u32 incl = x + (wid ? wsum[wid - 1] : 0u);
        u32 before = incl - s;
        if (before < RANK1 && incl >= RANK1) {
            u32 run = before;
            for (int b = 0; b < 16; ++b) {
                run += hist[b0 + b];
                if (run >= RANK1) { shu[2] = (u32)(b0 + b); break; }
            }
        }
        if (before < TOPK && incl >= TOPK) {
            u32 run = before;
            for (int b = 0; b < 16; ++b) {
                run += hist[b0 + b];
                if (run >= TOPK) { shu[3] = (u32)(b0 + b); break; }
            }
        }
    }
    __syncthreads();
    const u32 B1 = shu[2], B2 = shu[3];

    // ---- C: compact (wave-aggregated appends) ----
    for (int i = tid; i < CAP; i += 1024) cand[i] = ~0ull;
    __syncthreads();
    for (int a = 0; a < ADIM; ++a) {
        const float* base = cls + (2 * a + 1) * HWSZ;
        for (int r = 0; r < 6; ++r) {
            int hw = r * 1024 + tid;
            u32 fs = flip32(base[hw]);
            u32 bin = fs >> 18;
            u64 key = ((u64)fs << 32) | (u32)(hw * ADIM + a);
            bool inB2 = bin <= B2;
            bool tryS = inB2 && (bin <= B1);
            u32 posS = SCAP;
            u64 mS = __ballot(tryS ? 1 : 0);
            if (tryS) {
                int leader = __ffsll((unsigned long long)mS) - 1;
                u32 bbase = 0;
                if (lane == leader) bbase = atomicAdd(&shu[0], (u32)__popcll(mS));
                bbase = __shfl(bbase, leader, 64);
                posS = bbase + (u32)__popcll(mS & ((1ull << lane) - 1ull));
            }
            bool toL = inB2 && (!tryS || posS >= SCAP);
            u64 mL = __ballot(toL ? 1 : 0);
            if (toL) {
                int leader = __ffsll((unsigned long long)mL) - 1;
                u32 bbase = 0;
                if (lane == leader) bbase = atomicAdd(&shu[1], (u32)__popcll(mL));
                bbase = __shfl(bbase, leader, 64);
                u32 q = bbase + (u32)__popcll(mL & ((1ull << lane) - 1ull));
                if (q < LCAP) cand[CAP - 1 - q] = key;
            } else if (tryS && posS < SCAP) {
                cand[posS] = key;
            }
        }
    }
    __syncthreads();
    const u32 cs = shu[0], cl = shu[1];
    const bool fast = (cs <= SCAP);

    // ---- D: fast-path sort of 1024 slots + decode ----
    if (fast) {
        {   // in-wave stages k=2..64 (no barriers)
            u64 v = cand[tid];
            #pragma unroll
            for (int k = 2; k <= 64; k <<= 1)
                #pragma unroll
                for (int j = k >> 1; j >= 1; j >>= 1)
                    v = ce64(v, j, lane, ((tid & k) == 0));
            cand[tid] = v;
        }
        __syncthreads();
        for (int k = 128; k <= SCAP; k <<= 1) {
            for (int j = k >> 1; j >= 64; j >>= 1) {
                if (tid < SCAP / 2) {
                    u32 i = ((tid & ~(j - 1)) << 1) | (tid & (j - 1));
                    u32 l = i | (u32)j;
                    bool up = ((i & (u32)k) == 0);
                    u64 x = cand[i], y = cand[l];
                    if ((x > y) == up) { cand[i] = y; cand[l] = x; }
                }
                __syncthreads();
            }
            {   // in-wave j=32..1 merge (uniform direction per segment)
                u64 v = cand[tid];
                bool up = (((wid * 64) & k) == 0);
                #pragma unroll
                for (int j = 32; j >= 1; j >>= 1) v = ce64(v, j, lane, up);
                cand[tid] = v;
            }
            __syncthreads();
        }
        // decode sorted S boxes into LDS
        {
            u64 key = cand[tid];
            if ((u32)tid < cs) {
                float4 b = decode_box(loc, anc, (u32)key);
                sbox[tid] = b;
                sarea[tid] = (b.z - b.x) * (b.w - b.y);
            } else {
                sbox[tid] = make_float4(0.f, 0.f, 0.f, 0.f);
                sarea[tid] = 0.f;
            }
        }

        // ---- E: NMS over sorted S (boxes in LDS) ----
        const u32 limit = cs;
        while (true) {
            __syncthreads();
            u32 kc = shu[4], i0 = shu[5];
            if (kc >= OUTK || i0 >= limit) break;
            u32 ci = i0 + (u32)lane;
            bool valid = ci < limit;
            float4 c = sbox[valid ? ci : 0];
            float ca = sarea[valid ? ci : 0];

            bool sup = false;
            for (u32 j = (u32)wid; j < kc; j += 16)
                sup = sup || iou_gt(c, ca, kept[j], karea[j]);
            u64 bal = __ballot(sup ? 1 : 0);
            if (lane == 0) supw[wid] = bal;

            u64 sby = 0;
            u32 smax = 4u * wid + 4u; if (smax > 63u) smax = 63u;
            for (u32 s = 4u * wid + 1u; s <= smax; ++s) {
                u32 p = ((u32)lane + s) & 63u;
                if (p < (u32)lane && (i0 + p) < limit)
                    if (iou_gt(c, ca, sbox[i0 + p], sarea[i0 + p])) sby |= (1ull << p);
            }
            sbyp[wid * 64 + lane] = sby;
            __syncthreads();

            if (wid == 0) {
                u64 sup64 = 0, sbyfull = 0;
                #pragma unroll
                for (int w = 0; w < 16; ++w) { sup64 |= supw[w]; sbyfull |= sbyp[w * 64 + lane]; }
                bool ia = valid && !((sup64 >> lane) & 1);
                u64 A = __ballot(ia ? 1 : 0);
                for (int it = 0; it < 64; ++it) {
                    bool na = ia && ((sbyfull & A) == 0);
                    u64 A2 = __ballot(na ? 1 : 0);
                    if (A2 == A) break;
                    A = A2;
                }
                bool kp = (A >> lane) & 1;
                u32 rank = (u32)__popcll(A & ((1ull << lane) - 1ull));
                if (kp && kc + rank < OUTK) {
                    kept[kc + rank] = c; karea[kc + rank] = ca; out[kc + rank] = c;
                }
                if (lane == 0) {
                    u32 nk = kc + (u32)__popcll(A);
                    shu[4] = nk > OUTK ? OUTK : nk;
                    shu[5] = i0 + 64;
                }
            }
        }
    }

    // ---- Fallback: full 8192 sort + NMS w/ on-the-fly decode (rare) ----
    __syncthreads();
    const u32 kcF = shu[4];
    const u32 inL = cl < LCAP ? cl : LCAP;
    const u32 storedS = fast ? cs : SCAP;
    const u32 totalv = storedS + inL;
    const u32 limfb = totalv < TOPK ? totalv : TOPK;
    const u32 i0fb = fast ? cs : 0u;
    if (kcF < OUTK && i0fb < limfb) {
        for (int seg = wid; seg < CAP / 64; seg += 16) {
            u64 v = cand[seg * 64 + lane];
            #pragma unroll
            for (int k = 2; k <= 64; k <<= 1)
                #pragma unroll
                for (int j = k >> 1; j >= 1; j >>= 1)
                    v = ce64(v, j, lane, (((seg * 64 + lane) & k) == 0));
            cand[seg * 64 + lane] = v;
        }
        __syncthreads();
        for (int k = 128; k <= CAP; k <<= 1) {
            for (int j = k >> 1; j >= 64; j >>= 1) {
                for (u32 p = (u32)tid; p < CAP / 2; p += 1024) {
                    u32 i = ((p & ~(u32)(j - 1)) << 1) | (p & (u32)(j - 1));
                    u32 l = i | (u32)j;
                    bool up = ((i & (u32)k) == 0);
                    u64 x = cand[i], y = cand[l];
                    if ((x > y) == up) { cand[i] = y; cand[l] = x; }
                }
                __syncthreads();
            }
            for (int seg = wid; seg < CAP / 64; seg += 16) {
                u64 v = cand[seg * 64 + lane];
                bool up = (((seg * 64) & k) == 0);
                #pragma unroll
                for (int j = 32; j >= 1; j >>= 1) v = ce64(v, j, lane, up);
                cand[seg * 64 + lane] = v;
            }
            __syncthreads();
        }
        if (tid == 0) shu[5] = i0fb;
        while (true) {
            __syncthreads();
            u32 kc = shu[4], i0 = shu[5];
            if (kc >= OUTK || i0 >= limfb) break;
            if (wid == 0) {
                u32 ci = i0 + (u32)lane;
                u32 n = (ci < limfb) ? (u32)cand[ci] : 0u;
                float4 b = decode_box(loc, anc, n);
                cbox[lane] = b;
                carea[lane] = (b.z - b.x) * (b.w - b.y);
            }
            __syncthreads();
            u32 ci = i0 + (u32)lane;
            bool valid = ci < limfb;
            float4 c = cbox[lane];
            float ca = carea[lane];
            bool sup = false;
            for (u32 j = (u32)wid; j < kc; j += 16)
                sup = sup || iou_gt(c, ca, kept[j], karea[j]);
            u64 bal = __ballot(sup ? 1 : 0);
            if (lane == 0) supw[wid] = bal;
            u64 sby = 0;
            u32 smax = 4u * wid + 4u; if (smax > 63u) smax = 63u;
            for (u32 s = 4u * wid + 1u; s <= smax; ++s) {
                u32 p = ((u32)lane + s) & 63u;
                if (p < (u32)lane && (i0 + p) < limfb)
                    if (iou_gt(c, ca, cbox[p], carea[p])) sby |= (1ull << p);
            }
            sbyp[wid * 64 + lane] = sby;
            __syncthreads();
            if (wid == 0) {
                u64 sup64 = 0, sbyfull = 0;
                #pragma unroll
                for (int w = 0; w < 16; ++w) { sup64 |= supw[w]; sbyfull |= sbyp[w * 64 + lane]; }
                bool ia = valid && !((sup64 >> lane) & 1);
                u64 A = __ballot(ia ? 1 : 0);
                for (int it = 0; it < 64; ++it) {
                    bool na = ia && ((sbyfull & A) == 0);
                    u64 A2 = __ballot(na ? 1 : 0);
                    if (A2 == A) break;
                    A = A2;
                }
                bool kp = (A >> lane) & 1;
                u32 rank = (u32)__popcll(A & ((1ull << lane) - 1ull));
                if (kp && kc + rank < OUTK) {
                    kept[kc + rank] = c; karea[kc + rank] = ca; out[kc + rank] = c;
                }
                if (lane == 0) {
                    u32 nk = kc + (u32)__popcll(A);
                    shu[4] = nk > OUTK ? OUTK : nk;
                    shu[5] = i0 + 64;
                }
            }
        }
    }

    // ---- zero-pad ----
    __syncthreads();
    u32 kc = shu[4];
    for (u32 r = (u32)tid; r < OUTK; r += 1024)
        if (r >= kc) out[r] = make_float4(0.f, 0.f, 0.f, 0.f);
}

extern "C" void kernel_launch(void* const* d_in, const int* in_sizes, int n_in,
                              void* d_out, int out_size, void* d_ws, size_t ws_size,
                              hipStream_t stream) {
    const float* cls = (const float*)d_in[0];   // (1, 18, 64, 96)
    const float* loc = (const float*)d_in[1];   // (1, 36, 64, 96)
    const float* anc = (const float*)d_in[2];   // (55296, 4)
    k_mega<<<1, 1024, 0, stream>>>(cls, loc, anc, (float4*)d_out);
}